// Round 5
// baseline (1107.305 us; speedup 1.0000x reference)
//
#include <hip/hip_runtime.h>
#include <cstdint>

constexpr int BATCH = 128;
constexpr int H = 512, W = 512;
constexpr int HW = H * W;       // 2^18
constexpr int WPR = W / 64;     // 8 words per row
constexpr int WPI = HW / 64;    // 4096 words per image
constexpr int NSEED = 1000;
constexpr int MARGIN = 3000;    // expected candidate count for threshold select
constexpr int CAP2 = 4096;      // candidate list capacity (mean 3000, std ~55 -> 20 sigma)
constexpr int CAPS = 1024;      // small tie list capacity (mean ~32-64)

// ---------------- Threefry-2x32 (20 rounds), bit-exact vs JAX ----------------
__device__ __forceinline__ uint32_t rotl32(uint32_t v, int d) {
  return (v << d) | (v >> (32 - d));
}

__device__ __forceinline__ void tf2x32(uint32_t k0, uint32_t k1,
                                       uint32_t x0, uint32_t x1,
                                       uint32_t &o0, uint32_t &o1) {
  uint32_t ks2 = k0 ^ k1 ^ 0x1BD11BDAu;
  x0 += k0; x1 += k1;
  x0 += x1; x1 = rotl32(x1, 13); x1 ^= x0;
  x0 += x1; x1 = rotl32(x1, 15); x1 ^= x0;
  x0 += x1; x1 = rotl32(x1, 26); x1 ^= x0;
  x0 += x1; x1 = rotl32(x1, 6);  x1 ^= x0;
  x0 += k1; x1 += ks2 + 1u;
  x0 += x1; x1 = rotl32(x1, 17); x1 ^= x0;
  x0 += x1; x1 = rotl32(x1, 29); x1 ^= x0;
  x0 += x1; x1 = rotl32(x1, 16); x1 ^= x0;
  x0 += x1; x1 = rotl32(x1, 24); x1 ^= x0;
  x0 += ks2; x1 += k0 + 2u;
  x0 += x1; x1 = rotl32(x1, 13); x1 ^= x0;
  x0 += x1; x1 = rotl32(x1, 15); x1 ^= x0;
  x0 += x1; x1 = rotl32(x1, 26); x1 ^= x0;
  x0 += x1; x1 = rotl32(x1, 6);  x1 ^= x0;
  x0 += k0; x1 += k1 + 3u;
  x0 += x1; x1 = rotl32(x1, 17); x1 ^= x0;
  x0 += x1; x1 = rotl32(x1, 29); x1 ^= x0;
  x0 += x1; x1 = rotl32(x1, 16); x1 ^= x0;
  x0 += x1; x1 = rotl32(x1, 24); x1 ^= x0;
  x0 += k1; x1 += ks2 + 4u;
  x0 += x1; x1 = rotl32(x1, 13); x1 ^= x0;
  x0 += x1; x1 = rotl32(x1, 15); x1 ^= x0;
  x0 += x1; x1 = rotl32(x1, 26); x1 ^= x0;
  x0 += x1; x1 = rotl32(x1, 6);  x1 ^= x0;
  x0 += ks2; x1 += k0 + 5u;
  o0 = x0; o1 = x1;
}

__device__ __forceinline__ uint32_t score_bits(uint32_t k0, uint32_t k1, uint32_t i) {
  uint32_t a, c; tf2x32(k0, k1, 0u, i, a, c);
  return a ^ c;
}

// ---------------- per-image keys + nbr_bg + bg score threshold ----------------
__global__ void k_keys(uint32_t* __restrict__ keys, uint32_t* __restrict__ kbg,
                       uint32_t* __restrict__ Tbg) {
  int b = threadIdx.x;
  if (b >= BATCH) return;
  uint32_t kb0, kb1; tf2x32(0u, 42u, 0u, (uint32_t)b, kb0, kb1);
  uint32_t kf0, kf1; tf2x32(kb0, kb1, 0u, 0u, kf0, kf1);
  uint32_t kB0, kB1; tf2x32(kb0, kb1, 0u, 1u, kB0, kB1);
  uint32_t kz0, kz1; tf2x32(kb0, kb1, 0u, 2u, kz0, kz1);
  uint32_t za, zc; tf2x32(kz0, kz1, 0u, 0u, za, zc);
  uint32_t zb = za ^ zc;
  keys[b * 4 + 0] = kf0; keys[b * 4 + 1] = kf1;
  keys[b * 4 + 2] = kB0; keys[b * 4 + 3] = kB1;
  float uu = __uint_as_float((zb >> 9) | 0x3f800000u) - 1.0f;
  float span = __fsub_rn(0.7f, 0.3f);
  float z = __fadd_rn(__fmul_rn(uu, span), 0.3f);
  z = fmaxf(0.3f, z);
  float nb = ceilf(__fmul_rn(z, (float)HW));
  uint32_t K = (uint32_t)nb;
  kbg[b] = K;
  float tv = floorf((1.0f - (float)MARGIN / (float)K) * 8388608.0f);
  Tbg[b] = (uint32_t)fmaxf(tv, 0.0f);
}

// -------- fused x sweep: 256-bin int hist + 4096-bin float hist --------
__global__ __launch_bounds__(1024) void k_hist2(const float4* __restrict__ x4,
                                                uint32_t* __restrict__ gh256,
                                                uint32_t* __restrict__ ghbe) {
  __shared__ uint32_t h256[256];
  __shared__ uint32_t h4k[4096];
  int b = blockIdx.x >> 2, sub = blockIdx.x & 3, t = threadIdx.x;
  for (int i = t; i < 256; i += 1024) h256[i] = 0;
  for (int i = t; i < 4096; i += 1024) h4k[i] = 0;
  __syncthreads();
  const float4* xb = x4 + ((size_t)b * HW + (size_t)sub * (HW / 4)) / 4;
  for (int i = t; i < HW / 16; i += 1024) {
    float4 v4 = xb[i];
    float vv[4] = {v4.x, v4.y, v4.z, v4.w};
#pragma unroll
    for (int j = 0; j < 4; ++j) {
      float v = vv[j];
      int f = (int)floorf(__fmul_rn(v, 255.0f));
      f = min(max(f, 0), 255);
      atomicAdd(&h256[f], 1u);
      int g = (int)floorf(__fmul_rn(v, 4096.0f));
      g = min(max(g, 0), 4095);
      atomicAdd(&h4k[g], 1u);
    }
  }
  __syncthreads();
  for (int i = t; i < 256; i += 1024)
    if (h256[i]) atomicAdd(&gh256[(size_t)b * 256 + i], h256[i]);
  for (int i = t; i < 4096; i += 1024)
    if (h4k[i]) atomicAdd(&ghbe[(size_t)b * 4096 + i], h4k[i]);
}

// ------- block-parallel Otsu: exact associative_scan tree in LDS -------
__device__ __forceinline__ void lds_tree_cumsum256(float* L, float* S, int tid) {
  const int off[9] = {0, 256, 384, 448, 480, 496, 504, 508, 510};
  const int sz[9]  = {256, 128, 64, 32, 16, 8, 4, 2, 1};
  for (int l = 0; l < 8; ++l) {
    int o = off[l], on = off[l + 1], n = sz[l + 1];
    if (tid < n) L[on + tid] = __fadd_rn(L[o + 2 * tid], L[o + 2 * tid + 1]);
    __syncthreads();
  }
  if (tid == 0) S[off[8]] = L[off[8]];
  __syncthreads();
  for (int l = 7; l >= 0; --l) {
    int o = off[l], on = off[l + 1], hn = sz[l] / 2;
    if (tid == 0) S[o] = L[o];
    if (tid < hn) S[o + 2 * tid + 1] = S[on + tid];
    if (tid >= 1 && tid < hn) S[o + 2 * tid] = __fadd_rn(S[on + tid - 1], L[o + 2 * tid]);
    __syncthreads();
  }
}

__global__ __launch_bounds__(256) void k_otsu(const uint32_t* __restrict__ gh,
                                              int* __restrict__ th_out) {
  __shared__ float L[511], S[511], wc[256], mm[256];
  __shared__ float sv[256];
  __shared__ int si[256];
  int b = blockIdx.x, tid = threadIdx.x;
  uint32_t hv = gh[(size_t)b * 256 + tid];
  L[tid] = (float)hv;
  __syncthreads();
  lds_tree_cumsum256(L, S, tid);
  wc[tid] = S[tid];
  __syncthreads();
  L[tid] = __fmul_rn((float)hv, (float)tid);
  __syncthreads();
  lds_tree_cumsum256(L, S, tid);
  mm[tid] = S[tid];
  __syncthreads();
  float total = (float)HW;
  float mT = mm[255];
  {
    float w = wc[tid];
    float denom = __fmul_rn(w, __fsub_rn(total, w));
    float s = 0.0f;
    if (denom > 0.0f) {
      float d  = __fsub_rn(__fmul_rn(mT, w), __fmul_rn(total, mm[tid]));
      float nu = __fmul_rn(d, d);
      float dd = __fmul_rn(__fmul_rn(denom, total), total);
      s = __fdiv_rn(nu, dd);
    }
    sv[tid] = s; si[tid] = tid;
  }
  __syncthreads();
  for (int st = 128; st >= 1; st >>= 1) {
    if (tid < st) {
      float s2 = sv[tid + st]; int i2 = si[tid + st];
      if (s2 > sv[tid] || (s2 == sv[tid] && i2 < si[tid])) { sv[tid] = s2; si[tid] = i2; }
    }
    __syncthreads();
  }
  if (tid == 0) {
    int bi = si[0];
    if (bi == 0) bi = 1;
    if (bi == 255) bi = 254;
    th_out[b] = bi;
  }
}

// parallel scan (ascending), K per image -> crossing bin + rank within bin
__global__ __launch_bounds__(256) void k_scan_asc(const uint32_t* __restrict__ gh,
                                                  const uint32_t* __restrict__ Ka,
                                                  uint32_t* __restrict__ b1a,
                                                  uint32_t* __restrict__ r1a) {
  __shared__ uint32_t h[4096];
  __shared__ uint32_t ps[256];
  int b = blockIdx.x, tid = threadIdx.x;
  uint32_t K = Ka[b];
  const uint32_t* g = gh + (size_t)b * 4096;
  for (int i = tid; i < 4096; i += 256) h[i] = g[i];
  __syncthreads();
  uint32_t s = 0;
#pragma unroll
  for (int i = 0; i < 16; ++i) s += h[tid * 16 + i];
  ps[tid] = s;
  __syncthreads();
  if (tid == 0) {
    uint32_t acc = 0, b1 = 0, r1 = 1;
    for (int c = 0; c < 256; ++c) {
      if (acc + ps[c] >= K) {
        for (int bin = c * 16; bin < c * 16 + 16; ++bin) {
          uint32_t cc = h[bin];
          if (acc + cc >= K) { b1 = (uint32_t)bin; r1 = K - acc; break; }
          acc += cc;
        }
        break;
      }
      acc += ps[c];
    }
    b1a[b] = b1; r1a[b] = r1;
  }
}

// ---------------- ROI bitmap: bit = floor(x*255) > th --------------------
__global__ void k_roi(const float* __restrict__ x, const int* __restrict__ th,
                      uint64_t* __restrict__ roi) {
  int p = blockIdx.x * blockDim.x + threadIdx.x;
  int b = p >> 18;
  float v = x[p];
  int f = (int)floorf(__fmul_rn(v, 255.0f));
  bool pred = f > th[b];
  uint64_t bw = __ballot(pred);
  if ((threadIdx.x & 63) == 0) roi[p >> 6] = bw;
}

// ---------- erosion: 11-wide row min (OOB = 1), then 11-tall col min --------
__global__ void k_rowmin(const uint64_t* __restrict__ in, uint64_t* __restrict__ out) {
  int w = blockIdx.x * blockDim.x + threadIdx.x;
  int c = w & (WPR - 1);
  uint64_t cur = in[w];
  uint64_t left  = (c > 0)       ? in[w - 1] : ~0ull;
  uint64_t right = (c < WPR - 1) ? in[w + 1] : ~0ull;
  uint64_t res = cur;
#pragma unroll
  for (int s = 1; s <= 5; ++s) {
    res &= (cur >> s) | (right << (64 - s));
    res &= (cur << s) | (left >> (64 - s));
  }
  out[w] = res;
}

// col-min + per-image popcount + fg threshold, one block per image
__global__ __launch_bounds__(1024) void k_colmin_count(const uint64_t* __restrict__ in,
                                                       uint64_t* __restrict__ out,
                                                       uint32_t* __restrict__ Tfg) {
  __shared__ uint32_t red[16];
  int b = blockIdx.x, t = threadIdx.x;
  const uint64_t* ib = in + (size_t)b * WPI;
  uint64_t* ob = out + (size_t)b * WPI;
  uint32_t loc = 0;
  for (int w = t; w < WPI; w += 1024) {
    int r = w >> 3;
    uint64_t res = ib[w];
#pragma unroll
    for (int d = 1; d <= 5; ++d) {
      if (r >= d)     res &= ib[w - WPR * d];
      if (r + d < H)  res &= ib[w + WPR * d];
    }
    ob[w] = res;
    loc += (uint32_t)__popcll(res);
  }
  for (int s = 32; s >= 1; s >>= 1) loc += __shfl_down(loc, s);
  if ((t & 63) == 0) red[t >> 6] = loc;
  __syncthreads();
  if (t == 0) {
    uint32_t E = 0;
    for (int i = 0; i < 16; ++i) E += red[i];
    uint32_t T;
    if (E <= (uint32_t)NSEED) T = 0xFFFFFFFFu;
    else {
      float tv = floorf((1.0f - (float)MARGIN / (float)E) * 8388608.0f);
      T = (uint32_t)fmaxf(tv, 0.0f);
    }
    Tfg[b] = T;
  }
}

// ---- single threefry sweep: zero out-bitmap, append candidates v >= T ----
__global__ __launch_bounds__(1024) void k_selA(const uint64_t* __restrict__ elig,
                                               const uint32_t* __restrict__ keys, int koff,
                                               const uint32_t* __restrict__ Tv,
                                               uint32_t* __restrict__ cnt,
                                               uint64_t* __restrict__ list,
                                               uint64_t* __restrict__ out) {
  int b = blockIdx.x >> 2, sub = blockIdx.x & 3, t = threadIdx.x;
  const uint64_t* eb = elig + (size_t)b * WPI;
  uint64_t* ob = out + (size_t)b * WPI;
  uint32_t T = Tv[b];
  int wbase = sub * (WPI / 4);
  if (T == 0xFFFFFFFFu) {     // E <= NSEED: all eligible selected
    for (int w = t; w < WPI / 4; w += 1024) ob[wbase + w] = eb[wbase + w];
    return;
  }
  for (int w = t; w < WPI / 4; w += 1024) ob[wbase + w] = 0;
  uint32_t k0 = keys[b * 4 + koff], k1 = keys[b * 4 + koff + 1];
  uint32_t pbase = (uint32_t)(sub * (HW / 4));
  for (int i = t; i < HW / 4; i += 2048) {
    uint32_t p1 = pbase + (uint32_t)i;
    uint32_t p2 = p1 + 1024u;
    uint32_t v1 = score_bits(k0, k1, p1) >> 9;   // two independent chains for ILP
    uint32_t v2 = score_bits(k0, k1, p2) >> 9;
    bool e1 = (eb[p1 >> 6] >> (p1 & 63)) & 1ull;
    bool e2 = (eb[p2 >> 6] >> (p2 & 63)) & 1ull;
    if (e1 && v1 >= T) {
      uint32_t pos = atomicAdd(&cnt[b], 1u);
      if (pos < (uint32_t)CAP2)
        list[(size_t)b * CAP2 + pos] = (((uint64_t)((~v1) & 0x7FFFFFu)) << 18) | p1;
    }
    if (e2 && v2 >= T) {
      uint32_t pos = atomicAdd(&cnt[b], 1u);
      if (pos < (uint32_t)CAP2)
        list[(size_t)b * CAP2 + pos] = (((uint64_t)((~v2) & 0x7FFFFFu)) << 18) | p2;
    }
  }
}

// ---- exact in-block top-NSEED over candidate list (hist+scan+tie-rank) ----
__global__ __launch_bounds__(1024) void k_cut2xl(const uint32_t* __restrict__ Tv,
                                                 const uint32_t* __restrict__ cnt,
                                                 const uint64_t* __restrict__ list,
                                                 uint64_t* __restrict__ bm) {
  __shared__ uint32_t h[4096];
  __shared__ uint32_t S[256];
  __shared__ uint32_t sb2, sr2;
  __shared__ uint64_t tie[1024];
  __shared__ uint32_t tcnt;
  int b = blockIdx.x, t = threadIdx.x;
  if (Tv[b] == 0xFFFFFFFFu) return;
  int n = min((int)cnt[b], CAP2);
  if (n == 0) return;
  uint32_t target = (uint32_t)min(NSEED, n);
  const uint64_t* lb = list + (size_t)b * CAP2;
  uint64_t K0 = (t < n)        ? lb[t]        : 0;
  uint64_t K1 = (t + 1024 < n) ? lb[t + 1024] : 0;
  uint64_t K2 = (t + 2048 < n) ? lb[t + 2048] : 0;
  uint64_t K3 = (t + 3072 < n) ? lb[t + 3072] : 0;
  for (int i = t; i < 4096; i += 1024) h[i] = 0;
  if (t == 0) tcnt = 0;
  __syncthreads();
  if (t < n)        atomicAdd(&h[(uint32_t)(K0 >> 29)], 1u);
  if (t + 1024 < n) atomicAdd(&h[(uint32_t)(K1 >> 29)], 1u);
  if (t + 2048 < n) atomicAdd(&h[(uint32_t)(K2 >> 29)], 1u);
  if (t + 3072 < n) atomicAdd(&h[(uint32_t)(K3 >> 29)], 1u);
  __syncthreads();
  if (t < 256) {
    uint32_t s = 0;
#pragma unroll
    for (int i = 0; i < 16; ++i) s += h[t * 16 + i];
    S[t] = s;
  }
  __syncthreads();
  for (int st = 1; st < 256; st <<= 1) {      // Hillis-Steele inclusive prefix
    uint32_t v = 0;
    if (t < 256 && t >= st) v = S[t - st];
    __syncthreads();
    if (t < 256) S[t] += v;
    __syncthreads();
  }
  if (t < 256) {
    uint32_t before = (t == 0) ? 0u : S[t - 1];
    if (S[t] >= target && before < target) {
      uint32_t acc = before;
      for (int i = 0; i < 16; ++i) {
        uint32_t c = h[t * 16 + i];
        if (acc + c >= target) { sb2 = (uint32_t)(t * 16 + i); sr2 = target - acc; break; }
        acc += c;
      }
    }
  }
  __syncthreads();
  uint32_t b2 = sb2, r2 = sr2;
  // phase3: definite winners (bin < b2) set bits; ties (bin == b2) to LDS
#define PROC(KK, VALID) \
  if (VALID) { \
    uint32_t bin = (uint32_t)((KK) >> 29); \
    if (bin < b2) { \
      uint32_t p = (uint32_t)(KK) & 0x3FFFFu; \
      atomicOr((unsigned long long*)&bm[(size_t)b * WPI + (p >> 6)], 1ull << (p & 63)); \
    } else if (bin == b2) { \
      uint32_t pos = atomicAdd(&tcnt, 1u); \
      if (pos < 1024u) tie[pos] = (KK); \
    } \
  }
  PROC(K0, t < n) PROC(K1, t + 1024 < n) PROC(K2, t + 2048 < n) PROC(K3, t + 3072 < n)
#undef PROC
  __syncthreads();
  int m = min((int)tcnt, 1024);
  int r = min((int)r2, m);
  if (t < m) {
    uint64_t mk = tie[t];
    int rank = 0;
    for (int i = 0; i < m; ++i) rank += (tie[i] < mk) ? 1 : 0;
    if (rank < r) {
      uint32_t p = (uint32_t)mk & 0x3FFFFu;
      atomicOr((unsigned long long*)&bm[(size_t)b * WPI + (p >> 6)], 1ull << (p & 63));
    }
  }
}

// ---- bg eligibility pass: write (bin < b1) words + collect bin==b1 ties ----
__global__ __launch_bounds__(1024) void k_passB(const float* __restrict__ x,
                                                const uint32_t* __restrict__ b1a,
                                                uint32_t* __restrict__ cnt,
                                                uint64_t* __restrict__ list,
                                                uint64_t* __restrict__ out) {
  int b = blockIdx.x >> 2, sub = blockIdx.x & 3, t = threadIdx.x;
  uint32_t b1 = b1a[b];
  const float* xb = x + (size_t)b * HW;
  int wave = t >> 6, lane = t & 63;
  for (int wl = wave; wl < WPI / 4; wl += 16) {
    int w = sub * (WPI / 4) + wl;
    int p = (w << 6) | lane;
    float v = xb[p];
    int bin = (int)floorf(__fmul_rn(v, 4096.0f));
    bin = min(max(bin, 0), 4095);
    bool sel = (uint32_t)bin < b1;
    uint64_t bw = __ballot(sel);
    if (lane == 0) out[(size_t)b * WPI + w] = bw;
    if ((uint32_t)bin == b1) {
      uint32_t pos = atomicAdd(&cnt[b], 1u);
      if (pos < (uint32_t)CAPS)
        list[(size_t)b * CAPS + pos] = (((uint64_t)__float_as_uint(v)) << 18) | (uint32_t)p;
    }
  }
}

// ---- rank small tie list, OR winners into bitmap ----
__global__ __launch_bounds__(1024) void k_cut2s(const uint32_t* __restrict__ r1a,
                                                const uint32_t* __restrict__ cnt,
                                                const uint64_t* __restrict__ list,
                                                uint64_t* __restrict__ bm) {
  __shared__ uint64_t ks[CAPS];
  int b = blockIdx.x, t = threadIdx.x;
  int n = min((int)cnt[b], CAPS);
  if (n == 0) return;
  int r = min((int)r1a[b], n);
  if (t < n) ks[t] = list[(size_t)b * CAPS + t];
  __syncthreads();
  if (t < n) {
    uint64_t mk = ks[t];
    int rank = 0;
    for (int i = 0; i < n; ++i) rank += (ks[i] < mk) ? 1 : 0;
    if (rank < r) {
      uint32_t p = (uint32_t)(mk & 0x3FFFFull);
      atomicOr((unsigned long long*)&bm[(size_t)b * WPI + (p >> 6)], 1ull << (p & 63));
    }
  }
}

// -------- 3-wide row dilation (OR, OOB = 0) --------
__global__ void k_rowdil(const uint64_t* __restrict__ in, uint64_t* __restrict__ out) {
  int w = blockIdx.x * blockDim.x + threadIdx.x;
  int c = w & (WPR - 1);
  uint64_t cur = in[w];
  uint64_t left  = (c > 0)       ? in[w - 1] : 0ull;
  uint64_t right = (c < WPR - 1) ? in[w + 1] : 0ull;
  out[w] = cur | (cur << 1) | (left >> 63) | (cur >> 1) | (right << 63);
}

// -------- column dilation + overlap removal + compose --------
__global__ void k_compose(const uint64_t* __restrict__ fgrow, const uint64_t* __restrict__ bgrow,
                          int* __restrict__ out) {
  int p = blockIdx.x * blockDim.x + threadIdx.x;
  int q = p & (HW - 1);
  int r = q >> 9;
  int gw = p >> 6;
  uint64_t F = fgrow[gw], Bb = bgrow[gw];
  if (r > 0)     { F |= fgrow[gw - WPR]; Bb |= bgrow[gw - WPR]; }
  if (r < H - 1) { F |= fgrow[gw + WPR]; Bb |= bgrow[gw + WPR]; }
  uint64_t ov = F & Bb;
  F &= ~ov; Bb &= ~ov;
  int lane = p & 63;
  int val = ((F >> lane) & 1ull) ? 1 : (((Bb >> lane) & 1ull) ? 0 : -255);
  out[p] = val;
}

extern "C" void kernel_launch(void* const* d_in, const int* in_sizes, int n_in,
                              void* d_out, int out_size, void* d_ws, size_t ws_size,
                              hipStream_t stream) {
  (void)in_sizes; (void)n_in; (void)out_size; (void)ws_size;
  const float* x = (const float*)d_in[0];
  int* out = (int*)d_out;
  char* ws = (char*)d_ws;

  // ---- workspace layout ----
  uint32_t* keys = (uint32_t*)(ws + 0);       // 2048
  uint32_t* kbg  = (uint32_t*)(ws + 2048);    // 512
  int*      th   = (int*)     (ws + 2560);    // 512
  uint32_t* b1be = (uint32_t*)(ws + 3072);
  uint32_t* r1be = (uint32_t*)(ws + 3584);
  uint32_t* Tbg  = (uint32_t*)(ws + 4096);
  uint32_t* Tfg  = (uint32_t*)(ws + 4608);
  // zeroed region
  char* Z = ws + 8192;
  uint32_t* cnt_fg = (uint32_t*)(Z + 0);
  uint32_t* cnt_be = (uint32_t*)(Z + 512);
  uint32_t* cnt_bg = (uint32_t*)(Z + 1024);
  uint32_t* gh256  = (uint32_t*)(Z + 1536);             // 128*256*4 = 131072
  uint32_t* gh_be  = (uint32_t*)(Z + 1536 + 131072);    // 128*4096*4 = 2 MB
  size_t Zsize = 1536 + 131072 + 2097152;               // ~2.23 MB
  char* P = Z + Zsize;
  uint64_t* list    = (uint64_t*)(P + 0);               // 128*CAP2*8 = 4 MB (shared fg/bg)
  uint64_t* list_be = (uint64_t*)(P + 4194304);         // 128*CAPS*8 = 1 MB
  uint64_t* bmA = (uint64_t*)(P + 5242880);             // 4 MB each
  uint64_t* bmB = bmA + (size_t)BATCH * WPI;
  uint64_t* bmC = bmB + (size_t)BATCH * WPI;

  hipMemsetAsync(Z, 0, Zsize, stream);
  k_keys   <<<1, 128, 0, stream>>>(keys, kbg, Tbg);
  k_hist2  <<<BATCH * 4, 1024, 0, stream>>>((const float4*)x, gh256, gh_be);
  k_otsu   <<<BATCH, 256, 0, stream>>>(gh256, th);
  k_scan_asc<<<BATCH, 256, 0, stream>>>(gh_be, kbg, b1be, r1be);
  k_roi    <<<(BATCH * HW) / 256, 256, 0, stream>>>(x, th, bmA);
  k_rowmin <<<(BATCH * WPI) / 256, 256, 0, stream>>>(bmA, bmB);
  k_colmin_count<<<BATCH, 1024, 0, stream>>>(bmB, bmA, Tfg);   // eroded ROI in A + Tfg
  // fg select -> bmB
  k_selA   <<<BATCH * 4, 1024, 0, stream>>>(bmA, keys, 0, Tfg, cnt_fg, list, bmB);
  k_cut2xl <<<BATCH, 1024, 0, stream>>>(Tfg, cnt_fg, list, bmB);
  // bg eligibility -> bmC
  k_passB  <<<BATCH * 4, 1024, 0, stream>>>(x, b1be, cnt_be, list_be, bmC);
  k_cut2s  <<<BATCH, 1024, 0, stream>>>(r1be, cnt_be, list_be, bmC);
  // bg select -> bmA (list region reused; fg consumer already done)
  k_selA   <<<BATCH * 4, 1024, 0, stream>>>(bmC, keys, 2, Tbg, cnt_bg, list, bmA);
  k_cut2xl <<<BATCH, 1024, 0, stream>>>(Tbg, cnt_bg, list, bmA);
  // dilation + compose
  k_rowdil <<<(BATCH * WPI) / 256, 256, 0, stream>>>(bmB, bmC);   // fg row-dil in C
  k_rowdil <<<(BATCH * WPI) / 256, 256, 0, stream>>>(bmA, bmB);   // bg row-dil in B
  k_compose<<<(BATCH * HW) / 256, 256, 0, stream>>>(bmC, bmB, out);
}

// Round 6
// 539.251 us; speedup vs baseline: 2.0534x; 2.0534x over previous
//
#include <hip/hip_runtime.h>
#include <cstdint>

constexpr int BATCH = 128;
constexpr int H = 512, W = 512;
constexpr int HW = H * W;       // 2^18
constexpr int WPR = W / 64;     // 8 words per row
constexpr int WPI = HW / 64;    // 4096 words per image
constexpr int NSEED = 1000;
constexpr int MARGIN = 3000;    // expected candidate count for threshold select
constexpr int CAP2 = 4096;      // per-image candidate list capacity (mean 3000, +20 sigma)
constexpr int CAPS = 1024;      // small tie list capacity (mean ~32-64)
constexpr int LBUF = 2048;      // per-block LDS candidate buffer (mean 750, +48 sigma)

// ---------------- Threefry-2x32 (20 rounds), bit-exact vs JAX ----------------
__device__ __forceinline__ uint32_t rotl32(uint32_t v, int d) {
  return (v << d) | (v >> (32 - d));
}

__device__ __forceinline__ void tf2x32(uint32_t k0, uint32_t k1,
                                       uint32_t x0, uint32_t x1,
                                       uint32_t &o0, uint32_t &o1) {
  uint32_t ks2 = k0 ^ k1 ^ 0x1BD11BDAu;
  x0 += k0; x1 += k1;
  x0 += x1; x1 = rotl32(x1, 13); x1 ^= x0;
  x0 += x1; x1 = rotl32(x1, 15); x1 ^= x0;
  x0 += x1; x1 = rotl32(x1, 26); x1 ^= x0;
  x0 += x1; x1 = rotl32(x1, 6);  x1 ^= x0;
  x0 += k1; x1 += ks2 + 1u;
  x0 += x1; x1 = rotl32(x1, 17); x1 ^= x0;
  x0 += x1; x1 = rotl32(x1, 29); x1 ^= x0;
  x0 += x1; x1 = rotl32(x1, 16); x1 ^= x0;
  x0 += x1; x1 = rotl32(x1, 24); x1 ^= x0;
  x0 += ks2; x1 += k0 + 2u;
  x0 += x1; x1 = rotl32(x1, 13); x1 ^= x0;
  x0 += x1; x1 = rotl32(x1, 15); x1 ^= x0;
  x0 += x1; x1 = rotl32(x1, 26); x1 ^= x0;
  x0 += x1; x1 = rotl32(x1, 6);  x1 ^= x0;
  x0 += k0; x1 += k1 + 3u;
  x0 += x1; x1 = rotl32(x1, 17); x1 ^= x0;
  x0 += x1; x1 = rotl32(x1, 29); x1 ^= x0;
  x0 += x1; x1 = rotl32(x1, 16); x1 ^= x0;
  x0 += x1; x1 = rotl32(x1, 24); x1 ^= x0;
  x0 += k1; x1 += ks2 + 4u;
  x0 += x1; x1 = rotl32(x1, 13); x1 ^= x0;
  x0 += x1; x1 = rotl32(x1, 15); x1 ^= x0;
  x0 += x1; x1 = rotl32(x1, 26); x1 ^= x0;
  x0 += x1; x1 = rotl32(x1, 6);  x1 ^= x0;
  x0 += ks2; x1 += k0 + 5u;
  o0 = x0; o1 = x1;
}

__device__ __forceinline__ uint32_t score_bits(uint32_t k0, uint32_t k1, uint32_t i) {
  uint32_t a, c; tf2x32(k0, k1, 0u, i, a, c);
  return a ^ c;
}

// ---------------- per-image keys + nbr_bg + bg score threshold ----------------
__global__ void k_keys(uint32_t* __restrict__ keys, uint32_t* __restrict__ kbg,
                       uint32_t* __restrict__ Tbg) {
  int b = threadIdx.x;
  if (b >= BATCH) return;
  uint32_t kb0, kb1; tf2x32(0u, 42u, 0u, (uint32_t)b, kb0, kb1);
  uint32_t kf0, kf1; tf2x32(kb0, kb1, 0u, 0u, kf0, kf1);
  uint32_t kB0, kB1; tf2x32(kb0, kb1, 0u, 1u, kB0, kB1);
  uint32_t kz0, kz1; tf2x32(kb0, kb1, 0u, 2u, kz0, kz1);
  uint32_t za, zc; tf2x32(kz0, kz1, 0u, 0u, za, zc);
  uint32_t zb = za ^ zc;
  keys[b * 4 + 0] = kf0; keys[b * 4 + 1] = kf1;
  keys[b * 4 + 2] = kB0; keys[b * 4 + 3] = kB1;
  float uu = __uint_as_float((zb >> 9) | 0x3f800000u) - 1.0f;
  float span = __fsub_rn(0.7f, 0.3f);
  float z = __fadd_rn(__fmul_rn(uu, span), 0.3f);
  z = fmaxf(0.3f, z);
  float nb = ceilf(__fmul_rn(z, (float)HW));
  uint32_t K = (uint32_t)nb;
  kbg[b] = K;
  float tv = floorf((1.0f - (float)MARGIN / (float)K) * 8388608.0f);
  Tbg[b] = (uint32_t)fmaxf(tv, 0.0f);
}

// -------- fused x sweep: 256-bin int hist + 4096-bin float hist --------
__global__ __launch_bounds__(1024) void k_hist2(const float4* __restrict__ x4,
                                                uint32_t* __restrict__ gh256,
                                                uint32_t* __restrict__ ghbe) {
  __shared__ uint32_t h256[256];
  __shared__ uint32_t h4k[4096];
  int b = blockIdx.x >> 2, sub = blockIdx.x & 3, t = threadIdx.x;
  for (int i = t; i < 256; i += 1024) h256[i] = 0;
  for (int i = t; i < 4096; i += 1024) h4k[i] = 0;
  __syncthreads();
  const float4* xb = x4 + ((size_t)b * HW + (size_t)sub * (HW / 4)) / 4;
  for (int i = t; i < HW / 16; i += 1024) {
    float4 v4 = xb[i];
    float vv[4] = {v4.x, v4.y, v4.z, v4.w};
#pragma unroll
    for (int j = 0; j < 4; ++j) {
      float v = vv[j];
      int f = (int)floorf(__fmul_rn(v, 255.0f));
      f = min(max(f, 0), 255);
      atomicAdd(&h256[f], 1u);
      int g = (int)floorf(__fmul_rn(v, 4096.0f));
      g = min(max(g, 0), 4095);
      atomicAdd(&h4k[g], 1u);
    }
  }
  __syncthreads();
  for (int i = t; i < 256; i += 1024)
    if (h256[i]) atomicAdd(&gh256[(size_t)b * 256 + i], h256[i]);
  for (int i = t; i < 4096; i += 1024)
    if (h4k[i]) atomicAdd(&ghbe[(size_t)b * 4096 + i], h4k[i]);
}

// ------- block-parallel Otsu: exact associative_scan tree in LDS -------
__device__ __forceinline__ void lds_tree_cumsum256(float* L, float* S, int tid) {
  const int off[9] = {0, 256, 384, 448, 480, 496, 504, 508, 510};
  const int sz[9]  = {256, 128, 64, 32, 16, 8, 4, 2, 1};
  for (int l = 0; l < 8; ++l) {
    int o = off[l], on = off[l + 1], n = sz[l + 1];
    if (tid < n) L[on + tid] = __fadd_rn(L[o + 2 * tid], L[o + 2 * tid + 1]);
    __syncthreads();
  }
  if (tid == 0) S[off[8]] = L[off[8]];
  __syncthreads();
  for (int l = 7; l >= 0; --l) {
    int o = off[l], on = off[l + 1], hn = sz[l] / 2;
    if (tid == 0) S[o] = L[o];
    if (tid < hn) S[o + 2 * tid + 1] = S[on + tid];
    if (tid >= 1 && tid < hn) S[o + 2 * tid] = __fadd_rn(S[on + tid - 1], L[o + 2 * tid]);
    __syncthreads();
  }
}

__global__ __launch_bounds__(256) void k_otsu(const uint32_t* __restrict__ gh,
                                              int* __restrict__ th_out) {
  __shared__ float L[511], S[511], wc[256], mm[256];
  __shared__ float sv[256];
  __shared__ int si[256];
  int b = blockIdx.x, tid = threadIdx.x;
  uint32_t hv = gh[(size_t)b * 256 + tid];
  L[tid] = (float)hv;
  __syncthreads();
  lds_tree_cumsum256(L, S, tid);
  wc[tid] = S[tid];
  __syncthreads();
  L[tid] = __fmul_rn((float)hv, (float)tid);
  __syncthreads();
  lds_tree_cumsum256(L, S, tid);
  mm[tid] = S[tid];
  __syncthreads();
  float total = (float)HW;
  float mT = mm[255];
  {
    float w = wc[tid];
    float denom = __fmul_rn(w, __fsub_rn(total, w));
    float s = 0.0f;
    if (denom > 0.0f) {
      float d  = __fsub_rn(__fmul_rn(mT, w), __fmul_rn(total, mm[tid]));
      float nu = __fmul_rn(d, d);
      float dd = __fmul_rn(__fmul_rn(denom, total), total);
      s = __fdiv_rn(nu, dd);
    }
    sv[tid] = s; si[tid] = tid;
  }
  __syncthreads();
  for (int st = 128; st >= 1; st >>= 1) {
    if (tid < st) {
      float s2 = sv[tid + st]; int i2 = si[tid + st];
      if (s2 > sv[tid] || (s2 == sv[tid] && i2 < si[tid])) { sv[tid] = s2; si[tid] = i2; }
    }
    __syncthreads();
  }
  if (tid == 0) {
    int bi = si[0];
    if (bi == 0) bi = 1;
    if (bi == 255) bi = 254;
    th_out[b] = bi;
  }
}

// parallel scan (ascending), K per image -> crossing bin + rank within bin
__global__ __launch_bounds__(256) void k_scan_asc(const uint32_t* __restrict__ gh,
                                                  const uint32_t* __restrict__ Ka,
                                                  uint32_t* __restrict__ b1a,
                                                  uint32_t* __restrict__ r1a) {
  __shared__ uint32_t h[4096];
  __shared__ uint32_t ps[256];
  int b = blockIdx.x, tid = threadIdx.x;
  uint32_t K = Ka[b];
  const uint32_t* g = gh + (size_t)b * 4096;
  for (int i = tid; i < 4096; i += 256) h[i] = g[i];
  __syncthreads();
  uint32_t s = 0;
#pragma unroll
  for (int i = 0; i < 16; ++i) s += h[tid * 16 + i];
  ps[tid] = s;
  __syncthreads();
  if (tid == 0) {
    uint32_t acc = 0, b1 = 0, r1 = 1;
    for (int c = 0; c < 256; ++c) {
      if (acc + ps[c] >= K) {
        for (int bin = c * 16; bin < c * 16 + 16; ++bin) {
          uint32_t cc = h[bin];
          if (acc + cc >= K) { b1 = (uint32_t)bin; r1 = K - acc; break; }
          acc += cc;
        }
        break;
      }
      acc += ps[c];
    }
    b1a[b] = b1; r1a[b] = r1;
  }
}

// ---------------- ROI bitmap: bit = floor(x*255) > th --------------------
__global__ void k_roi(const float* __restrict__ x, const int* __restrict__ th,
                      uint64_t* __restrict__ roi) {
  int p = blockIdx.x * blockDim.x + threadIdx.x;
  int b = p >> 18;
  float v = x[p];
  int f = (int)floorf(__fmul_rn(v, 255.0f));
  bool pred = f > th[b];
  uint64_t bw = __ballot(pred);
  if ((threadIdx.x & 63) == 0) roi[p >> 6] = bw;
}

// ---------- erosion: 11-wide row min (OOB = 1), then 11-tall col min --------
__global__ void k_rowmin(const uint64_t* __restrict__ in, uint64_t* __restrict__ out) {
  int w = blockIdx.x * blockDim.x + threadIdx.x;
  int c = w & (WPR - 1);
  uint64_t cur = in[w];
  uint64_t left  = (c > 0)       ? in[w - 1] : ~0ull;
  uint64_t right = (c < WPR - 1) ? in[w + 1] : ~0ull;
  uint64_t res = cur;
#pragma unroll
  for (int s = 1; s <= 5; ++s) {
    res &= (cur >> s) | (right << (64 - s));
    res &= (cur << s) | (left >> (64 - s));
  }
  out[w] = res;
}

// col-min + per-image popcount + fg threshold, one block per image
__global__ __launch_bounds__(1024) void k_colmin_count(const uint64_t* __restrict__ in,
                                                       uint64_t* __restrict__ out,
                                                       uint32_t* __restrict__ Tfg) {
  __shared__ uint32_t red[16];
  int b = blockIdx.x, t = threadIdx.x;
  const uint64_t* ib = in + (size_t)b * WPI;
  uint64_t* ob = out + (size_t)b * WPI;
  uint32_t loc = 0;
  for (int w = t; w < WPI; w += 1024) {
    int r = w >> 3;
    uint64_t res = ib[w];
#pragma unroll
    for (int d = 1; d <= 5; ++d) {
      if (r >= d)     res &= ib[w - WPR * d];
      if (r + d < H)  res &= ib[w + WPR * d];
    }
    ob[w] = res;
    loc += (uint32_t)__popcll(res);
  }
  for (int s = 32; s >= 1; s >>= 1) loc += __shfl_down(loc, s);
  if ((t & 63) == 0) red[t >> 6] = loc;
  __syncthreads();
  if (t == 0) {
    uint32_t E = 0;
    for (int i = 0; i < 16; ++i) E += red[i];
    uint32_t T;
    if (E <= (uint32_t)NSEED) T = 0xFFFFFFFFu;
    else {
      float tv = floorf((1.0f - (float)MARGIN / (float)E) * 8388608.0f);
      T = (uint32_t)fmaxf(tv, 0.0f);
    }
    Tfg[b] = T;
  }
}

// ---- single threefry sweep: zero out-bitmap, LDS-buffered candidate append ----
__global__ __launch_bounds__(1024) void k_selA(const uint64_t* __restrict__ elig,
                                               const uint32_t* __restrict__ keys, int koff,
                                               const uint32_t* __restrict__ Tv,
                                               uint32_t* __restrict__ cnt,
                                               uint64_t* __restrict__ list,
                                               uint64_t* __restrict__ out) {
  __shared__ uint64_t lbuf[LBUF];
  __shared__ uint32_t lcnt;
  __shared__ uint32_t gbase;
  int b = blockIdx.x >> 2, sub = blockIdx.x & 3, t = threadIdx.x;
  const uint64_t* eb = elig + (size_t)b * WPI;
  uint64_t* ob = out + (size_t)b * WPI;
  uint32_t T = Tv[b];
  int wbase = sub * (WPI / 4);
  if (T == 0xFFFFFFFFu) {     // E <= NSEED: all eligible selected
    for (int w = t; w < WPI / 4; w += 1024) ob[wbase + w] = eb[wbase + w];
    return;
  }
  if (t == 0) lcnt = 0;
  for (int w = t; w < WPI / 4; w += 1024) ob[wbase + w] = 0;
  __syncthreads();
  uint32_t k0 = keys[b * 4 + koff], k1 = keys[b * 4 + koff + 1];
  uint32_t pbase = (uint32_t)(sub * (HW / 4));
  for (int i = t; i < HW / 4; i += 2048) {
    uint32_t p1 = pbase + (uint32_t)i;
    uint32_t p2 = p1 + 1024u;
    uint32_t v1 = score_bits(k0, k1, p1) >> 9;   // two independent chains for ILP
    uint32_t v2 = score_bits(k0, k1, p2) >> 9;
    bool e1 = (eb[p1 >> 6] >> (p1 & 63)) & 1ull;
    bool e2 = (eb[p2 >> 6] >> (p2 & 63)) & 1ull;
    if (e1 && v1 >= T) {
      uint32_t pos = atomicAdd(&lcnt, 1u);
      uint64_t key = (((uint64_t)((~v1) & 0x7FFFFFu)) << 18) | p1;
      if (pos < (uint32_t)LBUF) lbuf[pos] = key;
      else { uint32_t gp = atomicAdd(&cnt[b], 1u); if (gp < (uint32_t)CAP2) list[(size_t)b * CAP2 + gp] = key; }
    }
    if (e2 && v2 >= T) {
      uint32_t pos = atomicAdd(&lcnt, 1u);
      uint64_t key = (((uint64_t)((~v2) & 0x7FFFFFu)) << 18) | p2;
      if (pos < (uint32_t)LBUF) lbuf[pos] = key;
      else { uint32_t gp = atomicAdd(&cnt[b], 1u); if (gp < (uint32_t)CAP2) list[(size_t)b * CAP2 + gp] = key; }
    }
  }
  __syncthreads();
  int m = min((int)lcnt, LBUF);
  if (t == 0) gbase = atomicAdd(&cnt[b], (uint32_t)m);
  __syncthreads();
  uint32_t base = gbase;
  for (int i = t; i < m; i += 1024) {
    uint32_t pos = base + (uint32_t)i;
    if (pos < (uint32_t)CAP2) list[(size_t)b * CAP2 + pos] = lbuf[i];
  }
}

// ---- exact in-block top-NSEED over candidate list (hist+scan+tie-rank) ----
__global__ __launch_bounds__(1024) void k_cut2xl(const uint32_t* __restrict__ Tv,
                                                 const uint32_t* __restrict__ cnt,
                                                 const uint64_t* __restrict__ list,
                                                 uint64_t* __restrict__ bm) {
  __shared__ uint32_t h[4096];
  __shared__ uint32_t S[256];
  __shared__ uint32_t sb2, sr2;
  __shared__ uint64_t tie[1024];
  __shared__ uint32_t tcnt;
  int b = blockIdx.x, t = threadIdx.x;
  if (Tv[b] == 0xFFFFFFFFu) return;
  int n = min((int)cnt[b], CAP2);
  if (n == 0) return;
  uint32_t target = (uint32_t)min(NSEED, n);
  const uint64_t* lb = list + (size_t)b * CAP2;
  uint64_t K0 = (t < n)        ? lb[t]        : 0;
  uint64_t K1 = (t + 1024 < n) ? lb[t + 1024] : 0;
  uint64_t K2 = (t + 2048 < n) ? lb[t + 2048] : 0;
  uint64_t K3 = (t + 3072 < n) ? lb[t + 3072] : 0;
  for (int i = t; i < 4096; i += 1024) h[i] = 0;
  if (t == 0) tcnt = 0;
  __syncthreads();
  if (t < n)        atomicAdd(&h[(uint32_t)(K0 >> 29)], 1u);
  if (t + 1024 < n) atomicAdd(&h[(uint32_t)(K1 >> 29)], 1u);
  if (t + 2048 < n) atomicAdd(&h[(uint32_t)(K2 >> 29)], 1u);
  if (t + 3072 < n) atomicAdd(&h[(uint32_t)(K3 >> 29)], 1u);
  __syncthreads();
  if (t < 256) {
    uint32_t s = 0;
#pragma unroll
    for (int i = 0; i < 16; ++i) s += h[t * 16 + i];
    S[t] = s;
  }
  __syncthreads();
  for (int st = 1; st < 256; st <<= 1) {      // Hillis-Steele inclusive prefix
    uint32_t v = 0;
    if (t < 256 && t >= st) v = S[t - st];
    __syncthreads();
    if (t < 256) S[t] += v;
    __syncthreads();
  }
  if (t < 256) {
    uint32_t before = (t == 0) ? 0u : S[t - 1];
    if (S[t] >= target && before < target) {
      uint32_t acc = before;
      for (int i = 0; i < 16; ++i) {
        uint32_t c = h[t * 16 + i];
        if (acc + c >= target) { sb2 = (uint32_t)(t * 16 + i); sr2 = target - acc; break; }
        acc += c;
      }
    }
  }
  __syncthreads();
  uint32_t b2 = sb2, r2 = sr2;
#define PROC(KK, VALID) \
  if (VALID) { \
    uint32_t bin = (uint32_t)((KK) >> 29); \
    if (bin < b2) { \
      uint32_t p = (uint32_t)(KK) & 0x3FFFFu; \
      atomicOr((unsigned long long*)&bm[(size_t)b * WPI + (p >> 6)], 1ull << (p & 63)); \
    } else if (bin == b2) { \
      uint32_t pos = atomicAdd(&tcnt, 1u); \
      if (pos < 1024u) tie[pos] = (KK); \
    } \
  }
  PROC(K0, t < n) PROC(K1, t + 1024 < n) PROC(K2, t + 2048 < n) PROC(K3, t + 3072 < n)
#undef PROC
  __syncthreads();
  int m = min((int)tcnt, 1024);
  int r = min((int)r2, m);
  if (t < m) {
    uint64_t mk = tie[t];
    int rank = 0;
    for (int i = 0; i < m; ++i) rank += (tie[i] < mk) ? 1 : 0;
    if (rank < r) {
      uint32_t p = (uint32_t)mk & 0x3FFFFu;
      atomicOr((unsigned long long*)&bm[(size_t)b * WPI + (p >> 6)], 1ull << (p & 63));
    }
  }
}

// ---- bg eligibility pass: write (bin < b1) words + collect bin==b1 ties ----
__global__ __launch_bounds__(1024) void k_passB(const float* __restrict__ x,
                                                const uint32_t* __restrict__ b1a,
                                                uint32_t* __restrict__ cnt,
                                                uint64_t* __restrict__ list,
                                                uint64_t* __restrict__ out) {
  __shared__ uint64_t lbuf[512];
  __shared__ uint32_t lcnt;
  __shared__ uint32_t gbase;
  int b = blockIdx.x >> 2, sub = blockIdx.x & 3, t = threadIdx.x;
  uint32_t b1 = b1a[b];
  const float* xb = x + (size_t)b * HW;
  if (t == 0) lcnt = 0;
  __syncthreads();
  int wave = t >> 6, lane = t & 63;
  for (int wl = wave; wl < WPI / 4; wl += 16) {
    int w = sub * (WPI / 4) + wl;
    int p = (w << 6) | lane;
    float v = xb[p];
    int bin = (int)floorf(__fmul_rn(v, 4096.0f));
    bin = min(max(bin, 0), 4095);
    bool sel = (uint32_t)bin < b1;
    uint64_t bw = __ballot(sel);
    if (lane == 0) out[(size_t)b * WPI + w] = bw;
    if ((uint32_t)bin == b1) {
      uint32_t pos = atomicAdd(&lcnt, 1u);
      uint64_t key = (((uint64_t)__float_as_uint(v)) << 18) | (uint32_t)p;
      if (pos < 512u) lbuf[pos] = key;
      else { uint32_t gp = atomicAdd(&cnt[b], 1u); if (gp < (uint32_t)CAPS) list[(size_t)b * CAPS + gp] = key; }
    }
  }
  __syncthreads();
  int m = min((int)lcnt, 512);
  if (t == 0) gbase = atomicAdd(&cnt[b], (uint32_t)m);
  __syncthreads();
  uint32_t base = gbase;
  for (int i = t; i < m; i += 1024) {
    uint32_t pos = base + (uint32_t)i;
    if (pos < (uint32_t)CAPS) list[(size_t)b * CAPS + pos] = lbuf[i];
  }
}

// ---- rank small tie list, OR winners into bitmap ----
__global__ __launch_bounds__(1024) void k_cut2s(const uint32_t* __restrict__ r1a,
                                                const uint32_t* __restrict__ cnt,
                                                const uint64_t* __restrict__ list,
                                                uint64_t* __restrict__ bm) {
  __shared__ uint64_t ks[CAPS];
  int b = blockIdx.x, t = threadIdx.x;
  int n = min((int)cnt[b], CAPS);
  if (n == 0) return;
  int r = min((int)r1a[b], n);
  if (t < n) ks[t] = list[(size_t)b * CAPS + t];
  __syncthreads();
  if (t < n) {
    uint64_t mk = ks[t];
    int rank = 0;
    for (int i = 0; i < n; ++i) rank += (ks[i] < mk) ? 1 : 0;
    if (rank < r) {
      uint32_t p = (uint32_t)(mk & 0x3FFFFull);
      atomicOr((unsigned long long*)&bm[(size_t)b * WPI + (p >> 6)], 1ull << (p & 63));
    }
  }
}

// -------- 3-wide row dilation (OR, OOB = 0) --------
__global__ void k_rowdil(const uint64_t* __restrict__ in, uint64_t* __restrict__ out) {
  int w = blockIdx.x * blockDim.x + threadIdx.x;
  int c = w & (WPR - 1);
  uint64_t cur = in[w];
  uint64_t left  = (c > 0)       ? in[w - 1] : 0ull;
  uint64_t right = (c < WPR - 1) ? in[w + 1] : 0ull;
  out[w] = cur | (cur << 1) | (left >> 63) | (cur >> 1) | (right << 63);
}

// -------- column dilation + overlap removal + compose --------
__global__ void k_compose(const uint64_t* __restrict__ fgrow, const uint64_t* __restrict__ bgrow,
                          int* __restrict__ out) {
  int p = blockIdx.x * blockDim.x + threadIdx.x;
  int q = p & (HW - 1);
  int r = q >> 9;
  int gw = p >> 6;
  uint64_t F = fgrow[gw], Bb = bgrow[gw];
  if (r > 0)     { F |= fgrow[gw - WPR]; Bb |= bgrow[gw - WPR]; }
  if (r < H - 1) { F |= fgrow[gw + WPR]; Bb |= bgrow[gw + WPR]; }
  uint64_t ov = F & Bb;
  F &= ~ov; Bb &= ~ov;
  int lane = p & 63;
  int val = ((F >> lane) & 1ull) ? 1 : (((Bb >> lane) & 1ull) ? 0 : -255);
  out[p] = val;
}

extern "C" void kernel_launch(void* const* d_in, const int* in_sizes, int n_in,
                              void* d_out, int out_size, void* d_ws, size_t ws_size,
                              hipStream_t stream) {
  (void)in_sizes; (void)n_in; (void)out_size; (void)ws_size;
  const float* x = (const float*)d_in[0];
  int* out = (int*)d_out;
  char* ws = (char*)d_ws;

  // ---- workspace layout ----
  uint32_t* keys = (uint32_t*)(ws + 0);       // 2048
  uint32_t* kbg  = (uint32_t*)(ws + 2048);    // 512
  int*      th   = (int*)     (ws + 2560);    // 512
  uint32_t* b1be = (uint32_t*)(ws + 3072);
  uint32_t* r1be = (uint32_t*)(ws + 3584);
  uint32_t* Tbg  = (uint32_t*)(ws + 4096);
  uint32_t* Tfg  = (uint32_t*)(ws + 4608);
  // zeroed region
  char* Z = ws + 8192;
  uint32_t* cnt_fg = (uint32_t*)(Z + 0);
  uint32_t* cnt_be = (uint32_t*)(Z + 512);
  uint32_t* cnt_bg = (uint32_t*)(Z + 1024);
  uint32_t* gh256  = (uint32_t*)(Z + 1536);             // 128*256*4 = 131072
  uint32_t* gh_be  = (uint32_t*)(Z + 1536 + 131072);    // 128*4096*4 = 2 MB
  size_t Zsize = 1536 + 131072 + 2097152;               // ~2.23 MB
  char* P = Z + Zsize;
  uint64_t* list    = (uint64_t*)(P + 0);               // 128*CAP2*8 = 4 MB (shared fg/bg)
  uint64_t* list_be = (uint64_t*)(P + 4194304);         // 128*CAPS*8 = 1 MB
  uint64_t* bmA = (uint64_t*)(P + 5242880);             // 4 MB each
  uint64_t* bmB = bmA + (size_t)BATCH * WPI;
  uint64_t* bmC = bmB + (size_t)BATCH * WPI;

  hipMemsetAsync(Z, 0, Zsize, stream);
  k_keys   <<<1, 128, 0, stream>>>(keys, kbg, Tbg);
  k_hist2  <<<BATCH * 4, 1024, 0, stream>>>((const float4*)x, gh256, gh_be);
  k_otsu   <<<BATCH, 256, 0, stream>>>(gh256, th);
  k_scan_asc<<<BATCH, 256, 0, stream>>>(gh_be, kbg, b1be, r1be);
  k_roi    <<<(BATCH * HW) / 256, 256, 0, stream>>>(x, th, bmA);
  k_rowmin <<<(BATCH * WPI) / 256, 256, 0, stream>>>(bmA, bmB);
  k_colmin_count<<<BATCH, 1024, 0, stream>>>(bmB, bmA, Tfg);   // eroded ROI in A + Tfg
  // fg select -> bmB
  k_selA   <<<BATCH * 4, 1024, 0, stream>>>(bmA, keys, 0, Tfg, cnt_fg, list, bmB);
  k_cut2xl <<<BATCH, 1024, 0, stream>>>(Tfg, cnt_fg, list, bmB);
  // bg eligibility -> bmC
  k_passB  <<<BATCH * 4, 1024, 0, stream>>>(x, b1be, cnt_be, list_be, bmC);
  k_cut2s  <<<BATCH, 1024, 0, stream>>>(r1be, cnt_be, list_be, bmC);
  // bg select -> bmA (list region reused; fg consumer already done)
  k_selA   <<<BATCH * 4, 1024, 0, stream>>>(bmC, keys, 2, Tbg, cnt_bg, list, bmA);
  k_cut2xl <<<BATCH, 1024, 0, stream>>>(Tbg, cnt_bg, list, bmA);
  // dilation + compose
  k_rowdil <<<(BATCH * WPI) / 256, 256, 0, stream>>>(bmB, bmC);   // fg row-dil in C
  k_rowdil <<<(BATCH * WPI) / 256, 256, 0, stream>>>(bmA, bmB);   // bg row-dil in B
  k_compose<<<(BATCH * HW) / 256, 256, 0, stream>>>(bmC, bmB, out);
}

// Round 7
// 440.020 us; speedup vs baseline: 2.5165x; 1.2255x over previous
//
#include <hip/hip_runtime.h>
#include <cstdint>

constexpr int BATCH = 128;
constexpr int H = 512, W = 512;
constexpr int HW = H * W;       // 2^18
constexpr int WPR = W / 64;     // 8 words per row
constexpr int WPI = HW / 64;    // 4096 words per image
constexpr int NSEED = 1000;
constexpr int MARGIN = 3000;    // expected candidate count for threshold select
constexpr int CAP2 = 4096;      // per-image candidate list capacity (mean 3000, +20 sigma)
constexpr int CAPS = 1024;      // tie list capacity (mean ~64)
constexpr int LBUF = 2048;      // per-block LDS candidate buffer (mean 750)

// ---------------- Threefry-2x32 (20 rounds), bit-exact vs JAX ----------------
__device__ __forceinline__ uint32_t rotl32(uint32_t v, int d) {
  return (v << d) | (v >> (32 - d));
}

__device__ __forceinline__ void tf2x32(uint32_t k0, uint32_t k1,
                                       uint32_t x0, uint32_t x1,
                                       uint32_t &o0, uint32_t &o1) {
  uint32_t ks2 = k0 ^ k1 ^ 0x1BD11BDAu;
  x0 += k0; x1 += k1;
  x0 += x1; x1 = rotl32(x1, 13); x1 ^= x0;
  x0 += x1; x1 = rotl32(x1, 15); x1 ^= x0;
  x0 += x1; x1 = rotl32(x1, 26); x1 ^= x0;
  x0 += x1; x1 = rotl32(x1, 6);  x1 ^= x0;
  x0 += k1; x1 += ks2 + 1u;
  x0 += x1; x1 = rotl32(x1, 17); x1 ^= x0;
  x0 += x1; x1 = rotl32(x1, 29); x1 ^= x0;
  x0 += x1; x1 = rotl32(x1, 16); x1 ^= x0;
  x0 += x1; x1 = rotl32(x1, 24); x1 ^= x0;
  x0 += ks2; x1 += k0 + 2u;
  x0 += x1; x1 = rotl32(x1, 13); x1 ^= x0;
  x0 += x1; x1 = rotl32(x1, 15); x1 ^= x0;
  x0 += x1; x1 = rotl32(x1, 26); x1 ^= x0;
  x0 += x1; x1 = rotl32(x1, 6);  x1 ^= x0;
  x0 += k0; x1 += k1 + 3u;
  x0 += x1; x1 = rotl32(x1, 17); x1 ^= x0;
  x0 += x1; x1 = rotl32(x1, 29); x1 ^= x0;
  x0 += x1; x1 = rotl32(x1, 16); x1 ^= x0;
  x0 += x1; x1 = rotl32(x1, 24); x1 ^= x0;
  x0 += k1; x1 += ks2 + 4u;
  x0 += x1; x1 = rotl32(x1, 13); x1 ^= x0;
  x0 += x1; x1 = rotl32(x1, 15); x1 ^= x0;
  x0 += x1; x1 = rotl32(x1, 26); x1 ^= x0;
  x0 += x1; x1 = rotl32(x1, 6);  x1 ^= x0;
  x0 += ks2; x1 += k0 + 5u;
  o0 = x0; o1 = x1;
}

__device__ __forceinline__ uint32_t score_bits(uint32_t k0, uint32_t k1, uint32_t i) {
  uint32_t a, c; tf2x32(k0, k1, 0u, i, a, c);
  return a ^ c;
}

// ---------------- per-image keys + nbr_bg + bg score threshold ----------------
__global__ void k_keys(uint32_t* __restrict__ keys, uint32_t* __restrict__ kbg,
                       uint32_t* __restrict__ Tbg) {
  int b = threadIdx.x;
  if (b >= BATCH) return;
  uint32_t kb0, kb1; tf2x32(0u, 42u, 0u, (uint32_t)b, kb0, kb1);
  uint32_t kf0, kf1; tf2x32(kb0, kb1, 0u, 0u, kf0, kf1);
  uint32_t kB0, kB1; tf2x32(kb0, kb1, 0u, 1u, kB0, kB1);
  uint32_t kz0, kz1; tf2x32(kb0, kb1, 0u, 2u, kz0, kz1);
  uint32_t za, zc; tf2x32(kz0, kz1, 0u, 0u, za, zc);
  uint32_t zb = za ^ zc;
  keys[b * 4 + 0] = kf0; keys[b * 4 + 1] = kf1;
  keys[b * 4 + 2] = kB0; keys[b * 4 + 3] = kB1;
  float uu = __uint_as_float((zb >> 9) | 0x3f800000u) - 1.0f;
  float span = __fsub_rn(0.7f, 0.3f);
  float z = __fadd_rn(__fmul_rn(uu, span), 0.3f);
  z = fmaxf(0.3f, z);
  float nb = ceilf(__fmul_rn(z, (float)HW));
  uint32_t K = (uint32_t)nb;
  kbg[b] = K;
  float tv = floorf((1.0f - (float)MARGIN / (float)K) * 8388608.0f);
  Tbg[b] = (uint32_t)fmaxf(tv, 0.0f);
}

// -------- fused x sweep: 256-bin int hist + 4096-bin float hist --------
__global__ __launch_bounds__(1024) void k_hist2(const float4* __restrict__ x4,
                                                uint32_t* __restrict__ gh256,
                                                uint32_t* __restrict__ ghbe) {
  __shared__ uint32_t h256[256];
  __shared__ uint32_t h4k[4096];
  int b = blockIdx.x >> 2, sub = blockIdx.x & 3, t = threadIdx.x;
  for (int i = t; i < 256; i += 1024) h256[i] = 0;
  for (int i = t; i < 4096; i += 1024) h4k[i] = 0;
  __syncthreads();
  const float4* xb = x4 + ((size_t)b * HW + (size_t)sub * (HW / 4)) / 4;
  for (int i = t; i < HW / 16; i += 1024) {
    float4 v4 = xb[i];
    float vv[4] = {v4.x, v4.y, v4.z, v4.w};
#pragma unroll
    for (int j = 0; j < 4; ++j) {
      float v = vv[j];
      int f = (int)floorf(__fmul_rn(v, 255.0f));
      f = min(max(f, 0), 255);
      atomicAdd(&h256[f], 1u);
      int g = (int)floorf(__fmul_rn(v, 4096.0f));
      g = min(max(g, 0), 4095);
      atomicAdd(&h4k[g], 1u);
    }
  }
  __syncthreads();
  for (int i = t; i < 256; i += 1024)
    if (h256[i]) atomicAdd(&gh256[(size_t)b * 256 + i], h256[i]);
  for (int i = t; i < 4096; i += 1024)
    if (h4k[i]) atomicAdd(&ghbe[(size_t)b * 4096 + i], h4k[i]);
}

// ------- fused Otsu (blocks 0..127) + ascending K-scan (blocks 128..255) -------
__device__ __forceinline__ void lds_tree_cumsum256(float* L, float* S, int tid) {
  const int off[9] = {0, 256, 384, 448, 480, 496, 504, 508, 510};
  const int sz[9]  = {256, 128, 64, 32, 16, 8, 4, 2, 1};
  for (int l = 0; l < 8; ++l) {
    int o = off[l], on = off[l + 1], n = sz[l + 1];
    if (tid < n) L[on + tid] = __fadd_rn(L[o + 2 * tid], L[o + 2 * tid + 1]);
    __syncthreads();
  }
  if (tid == 0) S[off[8]] = L[off[8]];
  __syncthreads();
  for (int l = 7; l >= 0; --l) {
    int o = off[l], on = off[l + 1], hn = sz[l] / 2;
    if (tid == 0) S[o] = L[o];
    if (tid < hn) S[o + 2 * tid + 1] = S[on + tid];
    if (tid >= 1 && tid < hn) S[o + 2 * tid] = __fadd_rn(S[on + tid - 1], L[o + 2 * tid]);
    __syncthreads();
  }
}

__global__ __launch_bounds__(256) void k_otsu_scan(const uint32_t* __restrict__ gh256,
                                                   const uint32_t* __restrict__ ghbe,
                                                   const uint32_t* __restrict__ Ka,
                                                   int* __restrict__ th_out,
                                                   uint32_t* __restrict__ b1a,
                                                   uint32_t* __restrict__ r1a) {
  __shared__ float L[511], S[511], wc[256], mm[256];
  __shared__ float sv[256];
  __shared__ int si[256];
  __shared__ uint32_t h[4096];
  __shared__ uint32_t ps[256];
  int tid = threadIdx.x;
  if (blockIdx.x < BATCH) {
    int b = blockIdx.x;
    uint32_t hv = gh256[(size_t)b * 256 + tid];
    L[tid] = (float)hv;
    __syncthreads();
    lds_tree_cumsum256(L, S, tid);
    wc[tid] = S[tid];
    __syncthreads();
    L[tid] = __fmul_rn((float)hv, (float)tid);
    __syncthreads();
    lds_tree_cumsum256(L, S, tid);
    mm[tid] = S[tid];
    __syncthreads();
    float total = (float)HW;
    float mT = mm[255];
    {
      float w = wc[tid];
      float denom = __fmul_rn(w, __fsub_rn(total, w));
      float s = 0.0f;
      if (denom > 0.0f) {
        float d  = __fsub_rn(__fmul_rn(mT, w), __fmul_rn(total, mm[tid]));
        float nu = __fmul_rn(d, d);
        float dd = __fmul_rn(__fmul_rn(denom, total), total);
        s = __fdiv_rn(nu, dd);
      }
      sv[tid] = s; si[tid] = tid;
    }
    __syncthreads();
    for (int st = 128; st >= 1; st >>= 1) {
      if (tid < st) {
        float s2 = sv[tid + st]; int i2 = si[tid + st];
        if (s2 > sv[tid] || (s2 == sv[tid] && i2 < si[tid])) { sv[tid] = s2; si[tid] = i2; }
      }
      __syncthreads();
    }
    if (tid == 0) {
      int bi = si[0];
      if (bi == 0) bi = 1;
      if (bi == 255) bi = 254;
      th_out[b] = bi;
    }
  } else {
    int b = blockIdx.x - BATCH;
    uint32_t K = Ka[b];
    const uint32_t* g = ghbe + (size_t)b * 4096;
    for (int i = tid; i < 4096; i += 256) h[i] = g[i];
    __syncthreads();
    uint32_t s = 0;
#pragma unroll
    for (int i = 0; i < 16; ++i) s += h[tid * 16 + i];
    ps[tid] = s;
    __syncthreads();
    if (tid == 0) {
      uint32_t acc = 0, b1 = 0, r1 = 1;
      for (int c = 0; c < 256; ++c) {
        if (acc + ps[c] >= K) {
          for (int bin = c * 16; bin < c * 16 + 16; ++bin) {
            uint32_t cc = h[bin];
            if (acc + cc >= K) { b1 = (uint32_t)bin; r1 = K - acc; break; }
            acc += cc;
          }
          break;
        }
        acc += ps[c];
      }
      b1a[b] = b1; r1a[b] = r1;
    }
  }
}

// ==== mega-fused: ROI bits + 11x11 erosion + E count + bg elig compaction +
//      bg threefry candidates + bg tie collection. 4 blocks/image, 128 rows each.
__global__ __launch_bounds__(1024) void k_main(const float* __restrict__ x,
                                               const int* __restrict__ th,
                                               const uint32_t* __restrict__ b1a,
                                               const uint32_t* __restrict__ Tbg,
                                               const uint32_t* __restrict__ keys,
                                               uint32_t* __restrict__ Efg,
                                               uint32_t* __restrict__ cnt_bg,
                                               uint64_t* __restrict__ list,
                                               uint32_t* __restrict__ cnt_be,
                                               uint64_t* __restrict__ list_be,
                                               uint64_t* __restrict__ erod) {
  __shared__ uint64_t sroi[1104];   // roi bits, slab rows (<=138) x 8 words
  __shared__ uint64_t srow[1104];   // after 11-wide row min
  __shared__ uint32_t queue[8192];  // per-tile eligible pixel queue (max 16*512)
  __shared__ uint64_t lbuf[LBUF];   // candidate keys
  __shared__ uint32_t qcnt, lcnt, gbase;
  int b = blockIdx.x >> 2, sub = blockIdx.x & 3, t = threadIdx.x;
  int wave = t >> 6, lane = t & 63;
  int R0 = sub * 128;
  int rlo = max(R0 - 5, 0), rhi = min(R0 + 133, H);
  int nrows = rhi - rlo;
  int nwords = nrows * 8;
  const float* xb = x + (size_t)b * HW;
  int thv = th[b];
  uint32_t b1 = b1a[b];
  uint32_t T = Tbg[b];
  uint32_t k0 = keys[b * 4 + 2], k1 = keys[b * 4 + 3];
  if (t == 0) lcnt = 0;
  __syncthreads();
  // phase A: tiles of 128 slab words (16 rows); roi ballot + compaction + drain
  int ntiles = (nwords + 127) / 128;
  for (int tile = 0; tile < ntiles; ++tile) {
    if (t == 0) qcnt = 0;
    __syncthreads();
    int wbeg = tile * 128, wend = min(wbeg + 128, nwords);
    for (int wi = wbeg + wave; wi < wend; wi += 16) {
      int srow_i = wi >> 3, c = wi & 7;
      int absr = rlo + srow_i;
      int p = absr * W + c * 64 + lane;
      float v = xb[p];
      int f = (int)floorf(__fmul_rn(v, 255.0f));
      bool pred = f > thv;
      uint64_t bw = __ballot(pred);
      if (lane == 0) sroi[wi] = bw;
      if (absr >= R0 && absr < R0 + 128) {
        int bin = (int)floorf(__fmul_rn(v, 4096.0f));
        bin = min(max(bin, 0), 4095);
        bool elig = (uint32_t)bin < b1;
        uint64_t m = __ballot(elig);
        uint32_t base = 0;
        if (lane == 0 && m) base = atomicAdd(&qcnt, (uint32_t)__popcll(m));
        base = (uint32_t)__shfl((int)base, 0);
        if (elig) {
          uint32_t rank = (uint32_t)__popcll(m & ((1ull << lane) - 1ull));
          queue[base + rank] = (uint32_t)p;
        }
        if ((uint32_t)bin == b1) {   // rare (~64/image): direct global append
          uint32_t gp = atomicAdd(&cnt_be[b], 1u);
          if (gp < (uint32_t)CAPS)
            list_be[(size_t)b * CAPS + gp] =
                (((uint64_t)__float_as_uint(v)) << 18) | (uint32_t)p;
        }
      }
    }
    __syncthreads();
    uint32_t qn = qcnt;
    for (uint32_t i = t; i < qn; i += 1024) {
      uint32_t p = queue[i];
      uint32_t v = score_bits(k0, k1, p) >> 9;
      if (v >= T) {
        uint32_t pos = atomicAdd(&lcnt, 1u);
        uint64_t key = (((uint64_t)((~v) & 0x7FFFFFu)) << 18) | p;
        if (pos < (uint32_t)LBUF) lbuf[pos] = key;
        else { uint32_t gp = atomicAdd(&cnt_bg[b], 1u);
               if (gp < (uint32_t)CAP2) list[(size_t)b * CAP2 + gp] = key; }
      }
    }
    __syncthreads();
  }
  // 11-wide row min over slab
  for (int wi = t; wi < nwords; wi += 1024) {
    int c = wi & 7;
    uint64_t cur = sroi[wi];
    uint64_t left  = (c > 0) ? sroi[wi - 1] : ~0ull;
    uint64_t right = (c < 7) ? sroi[wi + 1] : ~0ull;
    uint64_t res = cur;
#pragma unroll
    for (int s = 1; s <= 5; ++s) {
      res &= (cur >> s) | (right << (64 - s));
      res &= (cur << s) | (left >> (64 - s));
    }
    srow[wi] = res;
  }
  __syncthreads();
  // 11-tall col min for core rows (exactly 1024 words) + popcount
  {
    int coreRow = t >> 3, c = t & 7;
    int absr = R0 + coreRow;
    int s = absr - rlo;
    uint64_t res = srow[s * 8 + c];
#pragma unroll
    for (int d = 1; d <= 5; ++d) {
      if (absr - d >= 0) res &= srow[(s - d) * 8 + c];
      if (absr + d < H)  res &= srow[(s + d) * 8 + c];
    }
    erod[(size_t)b * WPI + absr * 8 + c] = res;
    uint32_t pc = (uint32_t)__popcll(res);
    for (int sh = 32; sh >= 1; sh >>= 1) pc += __shfl_down(pc, sh);
    if (lane == 0 && pc) atomicAdd(&Efg[b], pc);
  }
  __syncthreads();
  // bulk candidate append
  int m = min((int)lcnt, LBUF);
  if (t == 0) gbase = atomicAdd(&cnt_bg[b], (uint32_t)m);
  __syncthreads();
  uint32_t base = gbase;
  for (int i = t; i < m; i += 1024) {
    uint32_t pos = base + (uint32_t)i;
    if (pos < (uint32_t)CAP2) list[(size_t)b * CAP2 + pos] = lbuf[i];
  }
}

// ---- rank bg tie list; winners (rank < r1) are eligible: add their threefry ----
__global__ __launch_bounds__(1024) void k_cut2s_ext(const uint32_t* __restrict__ r1a,
                                                    const uint32_t* __restrict__ cnt_be,
                                                    const uint64_t* __restrict__ list_be,
                                                    const uint32_t* __restrict__ Tbg,
                                                    const uint32_t* __restrict__ keys,
                                                    uint32_t* __restrict__ cnt_bg,
                                                    uint64_t* __restrict__ list) {
  __shared__ uint64_t ks[CAPS];
  int b = blockIdx.x, t = threadIdx.x;
  int n = min((int)cnt_be[b], CAPS);
  if (n == 0) return;
  int r = min((int)r1a[b], n);
  if (t < n) ks[t] = list_be[(size_t)b * CAPS + t];
  __syncthreads();
  if (t < n) {
    uint64_t mk = ks[t];
    int rank = 0;
    for (int i = 0; i < n; ++i) rank += (ks[i] < mk) ? 1 : 0;
    if (rank < r) {
      uint32_t p = (uint32_t)(mk & 0x3FFFFull);
      uint32_t v = score_bits(keys[b * 4 + 2], keys[b * 4 + 3], p) >> 9;
      if (v >= Tbg[b]) {
        uint32_t gp = atomicAdd(&cnt_bg[b], 1u);
        if (gp < (uint32_t)CAP2)
          list[(size_t)b * CAP2 + gp] = (((uint64_t)((~v) & 0x7FFFFFu)) << 18) | p;
      }
    }
  }
}

// ---- fg select sweep: T from Efg inline; copy path when E<=NSEED ----
__global__ __launch_bounds__(1024) void k_selfg(const uint64_t* __restrict__ elig,
                                                const uint32_t* __restrict__ keys,
                                                const uint32_t* __restrict__ Ea,
                                                uint32_t* __restrict__ cnt,
                                                uint64_t* __restrict__ list,
                                                uint64_t* __restrict__ out) {
  __shared__ uint64_t lbuf[LBUF];
  __shared__ uint32_t lcnt;
  __shared__ uint32_t gbase;
  int b = blockIdx.x >> 2, sub = blockIdx.x & 3, t = threadIdx.x;
  const uint64_t* eb = elig + (size_t)b * WPI;
  uint64_t* ob = out + (size_t)b * WPI;
  uint32_t E = Ea[b];
  int wbase = sub * (WPI / 4);
  if (E <= (uint32_t)NSEED) {     // all eligible selected
    for (int w = t; w < WPI / 4; w += 1024) ob[wbase + w] = eb[wbase + w];
    return;
  }
  float tvf = floorf((1.0f - (float)MARGIN / (float)E) * 8388608.0f);
  uint32_t T = (uint32_t)fmaxf(tvf, 0.0f);
  if (t == 0) lcnt = 0;
  for (int w = t; w < WPI / 4; w += 1024) ob[wbase + w] = 0;
  __syncthreads();
  uint32_t k0 = keys[b * 4 + 0], k1 = keys[b * 4 + 1];
  uint32_t pbase = (uint32_t)(sub * (HW / 4));
  for (int i = t; i < HW / 4; i += 2048) {
    uint32_t p1 = pbase + (uint32_t)i;
    uint32_t p2 = p1 + 1024u;
    uint32_t v1 = score_bits(k0, k1, p1) >> 9;
    uint32_t v2 = score_bits(k0, k1, p2) >> 9;
    bool e1 = (eb[p1 >> 6] >> (p1 & 63)) & 1ull;
    bool e2 = (eb[p2 >> 6] >> (p2 & 63)) & 1ull;
    if (e1 && v1 >= T) {
      uint32_t pos = atomicAdd(&lcnt, 1u);
      uint64_t key = (((uint64_t)((~v1) & 0x7FFFFFu)) << 18) | p1;
      if (pos < (uint32_t)LBUF) lbuf[pos] = key;
      else { uint32_t gp = atomicAdd(&cnt[b], 1u);
             if (gp < (uint32_t)CAP2) list[(size_t)b * CAP2 + gp] = key; }
    }
    if (e2 && v2 >= T) {
      uint32_t pos = atomicAdd(&lcnt, 1u);
      uint64_t key = (((uint64_t)((~v2) & 0x7FFFFFu)) << 18) | p2;
      if (pos < (uint32_t)LBUF) lbuf[pos] = key;
      else { uint32_t gp = atomicAdd(&cnt[b], 1u);
             if (gp < (uint32_t)CAP2) list[(size_t)b * CAP2 + gp] = key; }
    }
  }
  __syncthreads();
  int m = min((int)lcnt, LBUF);
  if (t == 0) gbase = atomicAdd(&cnt[b], (uint32_t)m);
  __syncthreads();
  uint32_t base = gbase;
  for (int i = t; i < m; i += 1024) {
    uint32_t pos = base + (uint32_t)i;
    if (pos < (uint32_t)CAP2) list[(size_t)b * CAP2 + pos] = lbuf[i];
  }
}

// ---- exact in-block top-NSEED over candidate list (hist+scan+tie-rank) ----
__global__ __launch_bounds__(1024) void k_cut2xl(const uint32_t* __restrict__ Ea,
                                                 const uint32_t* __restrict__ cnt,
                                                 const uint64_t* __restrict__ list,
                                                 uint64_t* __restrict__ bm) {
  __shared__ uint32_t h[4096];
  __shared__ uint32_t S[256];
  __shared__ uint32_t sb2, sr2;
  __shared__ uint64_t tie[1024];
  __shared__ uint32_t tcnt;
  int b = blockIdx.x, t = threadIdx.x;
  if (Ea[b] <= (uint32_t)NSEED) return;
  int n = min((int)cnt[b], CAP2);
  if (n == 0) return;
  uint32_t target = (uint32_t)min(NSEED, n);
  const uint64_t* lb = list + (size_t)b * CAP2;
  uint64_t K0 = (t < n)        ? lb[t]        : 0;
  uint64_t K1 = (t + 1024 < n) ? lb[t + 1024] : 0;
  uint64_t K2 = (t + 2048 < n) ? lb[t + 2048] : 0;
  uint64_t K3 = (t + 3072 < n) ? lb[t + 3072] : 0;
  for (int i = t; i < 4096; i += 1024) h[i] = 0;
  if (t == 0) tcnt = 0;
  __syncthreads();
  if (t < n)        atomicAdd(&h[(uint32_t)(K0 >> 29)], 1u);
  if (t + 1024 < n) atomicAdd(&h[(uint32_t)(K1 >> 29)], 1u);
  if (t + 2048 < n) atomicAdd(&h[(uint32_t)(K2 >> 29)], 1u);
  if (t + 3072 < n) atomicAdd(&h[(uint32_t)(K3 >> 29)], 1u);
  __syncthreads();
  if (t < 256) {
    uint32_t s = 0;
#pragma unroll
    for (int i = 0; i < 16; ++i) s += h[t * 16 + i];
    S[t] = s;
  }
  __syncthreads();
  for (int st = 1; st < 256; st <<= 1) {
    uint32_t v = 0;
    if (t < 256 && t >= st) v = S[t - st];
    __syncthreads();
    if (t < 256) S[t] += v;
    __syncthreads();
  }
  if (t < 256) {
    uint32_t before = (t == 0) ? 0u : S[t - 1];
    if (S[t] >= target && before < target) {
      uint32_t acc = before;
      for (int i = 0; i < 16; ++i) {
        uint32_t c = h[t * 16 + i];
        if (acc + c >= target) { sb2 = (uint32_t)(t * 16 + i); sr2 = target - acc; break; }
        acc += c;
      }
    }
  }
  __syncthreads();
  uint32_t b2 = sb2, r2 = sr2;
#define PROC(KK, VALID) \
  if (VALID) { \
    uint32_t bin = (uint32_t)((KK) >> 29); \
    if (bin < b2) { \
      uint32_t p = (uint32_t)(KK) & 0x3FFFFu; \
      atomicOr((unsigned long long*)&bm[(size_t)b * WPI + (p >> 6)], 1ull << (p & 63)); \
    } else if (bin == b2) { \
      uint32_t pos = atomicAdd(&tcnt, 1u); \
      if (pos < 1024u) tie[pos] = (KK); \
    } \
  }
  PROC(K0, t < n) PROC(K1, t + 1024 < n) PROC(K2, t + 2048 < n) PROC(K3, t + 3072 < n)
#undef PROC
  __syncthreads();
  int m = min((int)tcnt, 1024);
  int r = min((int)r2, m);
  if (t < m) {
    uint64_t mk = tie[t];
    int rank = 0;
    for (int i = 0; i < m; ++i) rank += (tie[i] < mk) ? 1 : 0;
    if (rank < r) {
      uint32_t p = (uint32_t)mk & 0x3FFFFu;
      atomicOr((unsigned long long*)&bm[(size_t)b * WPI + (p >> 6)], 1ull << (p & 63));
    }
  }
}

// -------- 3-wide row dilation for BOTH bitmaps in one launch --------
__global__ void k_rowdil2(const uint64_t* __restrict__ inF, uint64_t* __restrict__ outF,
                          const uint64_t* __restrict__ inG, uint64_t* __restrict__ outG) {
  int idx = blockIdx.x * blockDim.x + threadIdx.x;
  int half = BATCH * WPI;
  const uint64_t* in = (idx < half) ? inF : inG;
  uint64_t* out      = (idx < half) ? outF : outG;
  int w = (idx < half) ? idx : idx - half;
  int c = w & (WPR - 1);
  uint64_t cur = in[w];
  uint64_t left  = (c > 0)       ? in[w - 1] : 0ull;
  uint64_t right = (c < WPR - 1) ? in[w + 1] : 0ull;
  out[w] = cur | (cur << 1) | (left >> 63) | (cur >> 1) | (right << 63);
}

// -------- column dilation + overlap removal + compose --------
__global__ void k_compose(const uint64_t* __restrict__ fgrow, const uint64_t* __restrict__ bgrow,
                          int* __restrict__ out) {
  int p = blockIdx.x * blockDim.x + threadIdx.x;
  int q = p & (HW - 1);
  int r = q >> 9;
  int gw = p >> 6;
  uint64_t F = fgrow[gw], Bb = bgrow[gw];
  if (r > 0)     { F |= fgrow[gw - WPR]; Bb |= bgrow[gw - WPR]; }
  if (r < H - 1) { F |= fgrow[gw + WPR]; Bb |= bgrow[gw + WPR]; }
  uint64_t ov = F & Bb;
  F &= ~ov; Bb &= ~ov;
  int lane = p & 63;
  int val = ((F >> lane) & 1ull) ? 1 : (((Bb >> lane) & 1ull) ? 0 : -255);
  out[p] = val;
}

extern "C" void kernel_launch(void* const* d_in, const int* in_sizes, int n_in,
                              void* d_out, int out_size, void* d_ws, size_t ws_size,
                              hipStream_t stream) {
  (void)in_sizes; (void)n_in; (void)out_size; (void)ws_size;
  const float* x = (const float*)d_in[0];
  int* out = (int*)d_out;
  char* ws = (char*)d_ws;

  // ---- workspace layout ----
  uint32_t* keys = (uint32_t*)(ws + 0);       // 2048
  uint32_t* kbg  = (uint32_t*)(ws + 2048);    // 512
  int*      th   = (int*)     (ws + 2560);    // 512
  uint32_t* b1be = (uint32_t*)(ws + 3072);
  uint32_t* r1be = (uint32_t*)(ws + 3584);
  uint32_t* Tbg  = (uint32_t*)(ws + 4096);
  // zeroed region
  char* Z = ws + 8192;
  uint32_t* Efg    = (uint32_t*)(Z + 0);
  uint32_t* cnt_fg = (uint32_t*)(Z + 512);
  uint32_t* cnt_be = (uint32_t*)(Z + 1024);
  uint32_t* cnt_bg = (uint32_t*)(Z + 1536);
  uint32_t* gh256  = (uint32_t*)(Z + 2048);             // 131072
  uint32_t* gh_be  = (uint32_t*)(Z + 2048 + 131072);    // 2 MB
  uint64_t* bmG    = (uint64_t*)(Z + 2048 + 131072 + 2097152);  // 4 MB, bg select out
  size_t Zsize = 2048 + 131072 + 2097152 + 4194304;     // ~6.4 MB
  char* P = Z + Zsize;
  uint64_t* list    = (uint64_t*)(P + 0);               // 4 MB (bg then fg candidates)
  uint64_t* list_be = (uint64_t*)(P + 4194304);         // 1 MB (bg ties)
  uint64_t* bmE     = (uint64_t*)(P + 5242880);         // 4 MB eroded ROI
  uint64_t* bmF     = (uint64_t*)(P + 9437184);         // 4 MB fg select out
  uint64_t* D1      = bmE;                              // fg dilated (bmE dead by then)
  uint64_t* D2      = list;                             // bg dilated (list dead by then)

  hipMemsetAsync(Z, 0, Zsize, stream);
  k_keys      <<<1, 128, 0, stream>>>(keys, kbg, Tbg);
  k_hist2     <<<BATCH * 4, 1024, 0, stream>>>((const float4*)x, gh256, gh_be);
  k_otsu_scan <<<BATCH * 2, 256, 0, stream>>>(gh256, gh_be, kbg, th, b1be, r1be);
  k_main      <<<BATCH * 4, 1024, 0, stream>>>(x, th, b1be, Tbg, keys,
                                               Efg, cnt_bg, list, cnt_be, list_be, bmE);
  k_cut2s_ext <<<BATCH, 1024, 0, stream>>>(r1be, cnt_be, list_be, Tbg, keys, cnt_bg, list);
  k_cut2xl    <<<BATCH, 1024, 0, stream>>>(kbg, cnt_bg, list, bmG);   // bg -> bmG
  k_selfg     <<<BATCH * 4, 1024, 0, stream>>>(bmE, keys, Efg, cnt_fg, list, bmF);
  k_cut2xl    <<<BATCH, 1024, 0, stream>>>(Efg, cnt_fg, list, bmF);   // fg -> bmF
  k_rowdil2   <<<(2 * BATCH * WPI) / 256, 256, 0, stream>>>(bmF, D1, bmG, D2);
  k_compose   <<<(BATCH * HW) / 256, 256, 0, stream>>>(D1, D2, out);
}